// Round 4
// baseline (84.579 us; speedup 1.0000x reference)
//
#include <hip/hip_runtime.h>
#include <math.h>

#define N 384
#define DF 128
#define TEMP 2.0f
#define SOFT_LAMBDA 0.5f
#define BETA 1.0f
#define EPS_COS 1e-8f
#define EPS_LOG 1e-7f

// ---------------------------------------------------------------------------
// Kernel A: pairwise table pk[i][k] = {td, rd, eo (0 on diag), lo}.
// 24x24 grid of 16x16 tiles, 64 threads (1 wave). 2x2 register tiling with
// the dot-product identity sq = |a|^2 + |b|^2 - 2 a.b  (halves LDS reads and
// FMAs vs the diff-form outer product). Also zeroes d_out for kernel B's
// atomics (stream order guarantees completion before B starts).
// ---------------------------------------------------------------------------
__global__ __launch_bounds__(64) void rnc_pairs(
    const float* __restrict__ feat,   // [N, DF]
    const float* __restrict__ rg,     // [N, 3]
    const float* __restrict__ rr,     // [N, 3]
    const float* __restrict__ tr,     // [N, 3]
    const int*   __restrict__ sym,    // [N]
    float4* __restrict__ pk,          // [N*N]
    float* __restrict__ out)
{
    const int i0 = blockIdx.y * 16;
    const int k0 = blockIdx.x * 16;
    const int t = threadIdx.x;

    __shared__ __align__(16) float4 fa[16][33];  // 33-f4 stride: pad
    __shared__ __align__(16) float4 fb[16][33];
    __shared__ float nsq[2][16];
    __shared__ float4 hi_s[16], gi_s[16], ri_s[16];
    __shared__ float4 hk_s[16], gk_s[16], rk_s[16];

    if (blockIdx.x == 0 && blockIdx.y == 0 && t == 0) out[0] = 0.f;

    const float4* feat4 = reinterpret_cast<const float4*>(feat);
#pragma unroll
    for (int u = t; u < 512; u += 64) {
        int row = u >> 5, c = u & 31;
        fa[row][c] = feat4[(i0 + row) * (DF / 4) + c];
        fb[row][c] = feat4[(k0 + row) * (DF / 4) + c];
    }
    if (t < 16) {
        int g = i0 + t;
        hi_s[t] = make_float4(tr[g * 3], tr[g * 3 + 1], tr[g * 3 + 2],
                              (sym[g] == 1) ? 1.f : 0.f);
        float a = rg[g * 3], b = rg[g * 3 + 1], c = rg[g * 3 + 2];
        gi_s[t] = make_float4(a, b, c, fmaxf(sqrtf(a * a + b * b + c * c), EPS_COS));
        float d = rr[g * 3], e = rr[g * 3 + 1], f = rr[g * 3 + 2];
        ri_s[t] = make_float4(d, e, f, fmaxf(sqrtf(d * d + e * e + f * f), EPS_COS));
    } else if (t < 32) {
        int tl = t - 16, g = k0 + tl;
        hk_s[tl] = make_float4(tr[g * 3], tr[g * 3 + 1], tr[g * 3 + 2],
                               (sym[g] == 1) ? 1.f : 0.f);
        float a = rg[g * 3], b = rg[g * 3 + 1], c = rg[g * 3 + 2];
        gk_s[tl] = make_float4(a, b, c, fmaxf(sqrtf(a * a + b * b + c * c), EPS_COS));
        float d = rr[g * 3], e = rr[g * 3 + 1], f = rr[g * 3 + 2];
        rk_s[tl] = make_float4(d, e, f, fmaxf(sqrtf(d * d + e * e + f * f), EPS_COS));
    }
    __syncthreads();

    // row squared-norms (lanes 0..15: fa rows, 16..31: fb rows)
    if (t < 32) {
        int which = t >> 4, r = t & 15;
        float s = 0.f;
#pragma unroll
        for (int d4 = 0; d4 < DF / 4; ++d4) {
            float4 v = which ? fb[r][d4] : fa[r][d4];
            s += v.x * v.x + v.y * v.y + v.z * v.z + v.w * v.w;
        }
        nsq[which][r] = s;
    }
    __syncthreads();

    const int tx = t & 7, ty = t >> 3;
    const int ia = 2 * ty, ka = 2 * tx;
    float d00 = 0.f, d01 = 0.f, d10 = 0.f, d11 = 0.f;
#pragma unroll
    for (int d4 = 0; d4 < DF / 4; ++d4) {
        float4 a0 = fa[ia][d4];
        float4 a1 = fa[ia + 1][d4];
        float4 b0 = fb[ka][d4];
        float4 b1 = fb[ka + 1][d4];
        d00 += a0.x * b0.x + a0.y * b0.y + a0.z * b0.z + a0.w * b0.w;
        d01 += a0.x * b1.x + a0.y * b1.y + a0.z * b1.z + a0.w * b1.w;
        d10 += a1.x * b0.x + a1.y * b0.y + a1.z * b0.z + a1.w * b0.w;
        d11 += a1.x * b1.x + a1.y * b1.y + a1.z * b1.z + a1.w * b1.w;
    }
    float dots[2][2] = {{d00, d01}, {d10, d11}};

#pragma unroll
    for (int ii = 0; ii < 2; ++ii) {
#pragma unroll
        for (int kk = 0; kk < 2; ++kk) {
            const int li = ia + ii, lk = ka + kk;
            const int gi = i0 + li, gk = k0 + lk;
            float sq = nsq[0][li] + nsq[1][lk] - 2.f * dots[ii][kk];
            float dist = (sq > 0.f) ? sqrtf(sq) : 0.f;
            float lo = -dist * (1.0f / TEMP);
            float eo = (gi == gk) ? 0.f : expf(lo);

            float4 ha = hi_s[li], hb = hk_s[lk];
            float d0 = ha.x - hb.x, d1 = ha.y - hb.y, d2 = ha.z - hb.z;
            float a0 = fabsf(d0), a1 = fabsf(d1), a2 = fabsf(d2);
            float s = ((a0 < BETA) ? (0.5f * d0 * d0 / BETA) : (a0 - 0.5f * BETA))
                    + ((a1 < BETA) ? (0.5f * d1 * d1 / BETA) : (a1 - 0.5f * BETA))
                    + ((a2 < BETA) ? (0.5f * d2 * d2 / BETA) : (a2 - 0.5f * BETA));
            float td = s * (1.0f / 3.0f);

            float4 ga = gi_s[li], gb = gk_s[lk];
            float gdiff = 1.0f - (ga.x * gb.x + ga.y * gb.y + ga.z * gb.z) / (ga.w * gb.w);
            float4 ra = ri_s[li], rb = rk_s[lk];
            float rdiff = 1.0f - (ra.x * rb.x + ra.y * rb.y + ra.z * rb.z) / (ra.w * rb.w);
            bool pair_sym = (ha.w != 0.f) || (hb.w != 0.f);
            float rd = pair_sym ? gdiff : (gdiff + rdiff);

            pk[gi * N + gk] = make_float4(td, rd, eo, lo);
        }
    }
}

// ---------------------------------------------------------------------------
// Kernel B: rank denominators + pos terms + direct atomic reduction to out.
// 768 blocks (row i = b>>1, j-half h = b&1) x 512 threads. Lane l holds 3 j's
// in registers; wave w covers k in [w*48, w*48+48). Inner loop is at the VALU
// floor (~6 ops per (j,k) pair).
// ---------------------------------------------------------------------------
__global__ __launch_bounds__(512) void rnc_rank(
    const float4* __restrict__ pk,
    float* __restrict__ out)
{
    const int i = blockIdx.x >> 1;
    const int h = blockIdx.x & 1;
    const int t = threadIdx.x;

    __shared__ __align__(16) float4 pks[N];      // 6 KB
    __shared__ __align__(16) float2 dp[192][8];  // 12 KB
    __shared__ float red_h[8], red_t[8];

    if (t < N) pks[t] = pk[i * N + t];
    __syncthreads();

    const int w = t >> 6, l = t & 63;
    const int jl = l * 3;
    float tdj[3], rdj[3];
    float dent[3] = {0.f, 0.f, 0.f};
    float denh[3] = {0.f, 0.f, 0.f};
#pragma unroll
    for (int jj = 0; jj < 3; ++jj) {
        float4 p = pks[h * 192 + jl + jj];
        tdj[jj] = p.x;
        rdj[jj] = p.y;
    }
    const int k0 = w * 48;
#pragma unroll 4
    for (int k = k0; k < k0 + 48; ++k) {
        float4 p = pks[k];  // wave-uniform -> broadcast, conflict-free
#pragma unroll
        for (int jj = 0; jj < 3; ++jj) {
            bool mt = p.x >= tdj[jj];
            bool mh = mt && (p.y >= rdj[jj]);
            dent[jj] += mt ? p.z : 0.f;
            denh[jj] += mh ? p.z : 0.f;
        }
    }
#pragma unroll
    for (int jj = 0; jj < 3; ++jj) dp[jl + jj][w] = make_float2(dent[jj], denh[jj]);
    __syncthreads();

    float pos_h = 0.f, pos_t = 0.f;
    if (t < 192) {
        const int j = h * 192 + t;
        if (j != i) {
            float st_ = 0.f, sh_ = 0.f;
#pragma unroll
            for (int g = 0; g < 8; ++g) {
                float2 v = dp[t][g];
                st_ += v.x;
                sh_ += v.y;
            }
            float lo = pks[j].w;
            pos_h = lo - logf(sh_ + EPS_LOG);
            pos_t = lo - logf(st_ + EPS_LOG);
        }
    }
#pragma unroll
    for (int off = 32; off > 0; off >>= 1) {
        pos_h += __shfl_down(pos_h, off, 64);
        pos_t += __shfl_down(pos_t, off, 64);
    }
    if (l == 0) {
        red_h[w] = pos_h;
        red_t[w] = pos_t;
    }
    __syncthreads();
    if (t == 0) {
        float sh = 0.f, st = 0.f;
#pragma unroll
        for (int g = 0; g < 8; ++g) {
            sh += red_h[g];
            st += red_t[g];
        }
        const float scale = -1.0f / ((float)N * (float)(N - 1));
        atomicAdd(out, (sh + SOFT_LAMBDA * st) * scale);
    }
}

extern "C" void kernel_launch(void* const* d_in, const int* in_sizes, int n_in,
                              void* d_out, int out_size, void* d_ws, size_t ws_size,
                              hipStream_t stream) {
    const float* feat = (const float*)d_in[0];  // [384,128]
    const float* rg   = (const float*)d_in[1];  // [384,3]
    const float* rr   = (const float*)d_in[2];  // [384,3]
    const float* tr   = (const float*)d_in[3];  // [384,3]
    const int*   sym  = (const int*)d_in[4];    // [384,1]
    float* out = (float*)d_out;

    float4* pk = (float4*)d_ws;  // 384*384*16 B = 2.36 MB

    dim3 gridA(N / 16, N / 16);
    rnc_pairs<<<gridA, 64, 0, stream>>>(feat, rg, rr, tr, sym, pk, out);
    rnc_rank<<<2 * N, 512, 0, stream>>>(pk, out);
}

// Round 5
// 81.671 us; speedup vs baseline: 1.0356x; 1.0356x over previous
//
#include <hip/hip_runtime.h>
#include <math.h>

#define N 384
#define DF 128
#define TI 16
#define TK 16
#define TEMP 2.0f
#define SOFT_LAMBDA 0.5f
#define BETA 1.0f
#define EPS_COS 1e-8f
#define EPS_LOG 1e-7f

// ---------------------------------------------------------------------------
// Kernel A: pairwise table pk[i][k] = {td, rd, eo (0 on diag), lo}.
// 24x24 blocks of 16x16 pairs, 256 threads (round-3 structure: measured good;
// the 64-thread 2x2-tiled variant regressed ~5us from exposed latency).
// Also zeroes d_out for kernel B's atomics (kernel boundary orders it).
// ---------------------------------------------------------------------------
__global__ __launch_bounds__(256) void rnc_pairs(
    const float* __restrict__ feat,   // [N, DF]
    const float* __restrict__ rg,     // [N, 3]
    const float* __restrict__ rr,     // [N, 3]
    const float* __restrict__ tr,     // [N, 3]
    const int*   __restrict__ sym,    // [N]
    float4* __restrict__ pk,          // [N*N]
    float* __restrict__ out)
{
    const int i0 = blockIdx.y * TI;
    const int k0 = blockIdx.x * TK;
    const int t = threadIdx.x;

    __shared__ __align__(16) float4 fi_s[TI][DF / 4 + 1];
    __shared__ __align__(16) float4 fk_s[TK][DF / 4 + 1];
    __shared__ float4 hi_s[TI], gi_s[TI], ri_s[TI];
    __shared__ float4 hk_s[TK], gk_s[TK], rk_s[TK];

    if (blockIdx.x == 0 && blockIdx.y == 0 && t == 0) out[0] = 0.f;

    if (t < TI) {
        int g = i0 + t;
        hi_s[t] = make_float4(tr[g * 3], tr[g * 3 + 1], tr[g * 3 + 2],
                              (sym[g] == 1) ? 1.f : 0.f);
        float a = rg[g * 3], b = rg[g * 3 + 1], c = rg[g * 3 + 2];
        gi_s[t] = make_float4(a, b, c, fmaxf(sqrtf(a * a + b * b + c * c), EPS_COS));
        float d = rr[g * 3], e = rr[g * 3 + 1], f = rr[g * 3 + 2];
        ri_s[t] = make_float4(d, e, f, fmaxf(sqrtf(d * d + e * e + f * f), EPS_COS));
    } else if (t >= 32 && t < 32 + TK) {
        int g = k0 + (t - 32);
        int tl = t - 32;
        hk_s[tl] = make_float4(tr[g * 3], tr[g * 3 + 1], tr[g * 3 + 2],
                               (sym[g] == 1) ? 1.f : 0.f);
        float a = rg[g * 3], b = rg[g * 3 + 1], c = rg[g * 3 + 2];
        gk_s[tl] = make_float4(a, b, c, fmaxf(sqrtf(a * a + b * b + c * c), EPS_COS));
        float d = rr[g * 3], e = rr[g * 3 + 1], f = rr[g * 3 + 2];
        rk_s[tl] = make_float4(d, e, f, fmaxf(sqrtf(d * d + e * e + f * f), EPS_COS));
    }

    const float4* feat4 = reinterpret_cast<const float4*>(feat);
#pragma unroll
    for (int idx = 0; idx < 2; ++idx) {
        int u = t + idx * 256;            // 0..511 over 16 rows x 32 f4
        int row = u >> 5, c = u & 31;
        fi_s[row][c] = feat4[(i0 + row) * (DF / 4) + c];
        fk_s[row][c] = feat4[(k0 + row) * (DF / 4) + c];
    }
    __syncthreads();

    const int ii = t >> 4, kk = t & 15;
    float sq = 0.f;
#pragma unroll
    for (int d = 0; d < DF / 4; ++d) {
        float4 a = fi_s[ii][d];
        float4 b = fk_s[kk][d];
        float dx = a.x - b.x, dy = a.y - b.y, dz = a.z - b.z, dw = a.w - b.w;
        sq += dx * dx + dy * dy + dz * dz + dw * dw;
    }
    const int gi = i0 + ii, gk = k0 + kk;
    float dist = (sq > 0.f) ? sqrtf(sq) : 0.f;
    float lo = -dist * (1.0f / TEMP);
    float eo = (gi == gk) ? 0.f : expf(lo);

    float4 ha = hi_s[ii], hb = hk_s[kk];
    float d0 = ha.x - hb.x, d1 = ha.y - hb.y, d2 = ha.z - hb.z;
    float a0 = fabsf(d0), a1 = fabsf(d1), a2 = fabsf(d2);
    float s = ((a0 < BETA) ? (0.5f * d0 * d0 / BETA) : (a0 - 0.5f * BETA))
            + ((a1 < BETA) ? (0.5f * d1 * d1 / BETA) : (a1 - 0.5f * BETA))
            + ((a2 < BETA) ? (0.5f * d2 * d2 / BETA) : (a2 - 0.5f * BETA));
    float td = s * (1.0f / 3.0f);

    float4 ga = gi_s[ii], gb = gk_s[kk];
    float gdiff = 1.0f - (ga.x * gb.x + ga.y * gb.y + ga.z * gb.z) / (ga.w * gb.w);
    float4 ra = ri_s[ii], rb = rk_s[kk];
    float rdiff = 1.0f - (ra.x * rb.x + ra.y * rb.y + ra.z * rb.z) / (ra.w * rb.w);
    bool pair_sym = (ha.w != 0.f) || (hb.w != 0.f);
    float rd = pair_sym ? gdiff : (gdiff + rdiff);

    pk[gi * N + gk] = make_float4(td, rd, eo, lo);
}

// ---------------------------------------------------------------------------
// Kernel B: rank denominators + pos terms + atomic reduction to out.
// 384 blocks (one per row) x 512 threads (8 waves). Lane l holds 6 j's
// (j = l*6+jj, all 384 j per wave); wave w covers k in [w*48, w*48+48).
// One broadcast ds_read_b128 per k serves 12 accumulator chains -> LDS issue
// pipe halved vs the 2-blocks/row layout; VALU (~4.3us total) now binds.
// ---------------------------------------------------------------------------
__global__ __launch_bounds__(512) void rnc_rank(
    const float4* __restrict__ pk,
    float* __restrict__ out)
{
    const int i = blockIdx.x;
    const int t = threadIdx.x;

    __shared__ __align__(16) float4 pks[N];    // 6 KB
    __shared__ float dpt[8][N];                // 12 KB: [wave][j] den_t partial
    __shared__ float dph[8][N];                // 12 KB
    __shared__ float red_h[8], red_t[8];

    if (t < N) pks[t] = pk[i * N + t];
    __syncthreads();

    const int w = t >> 6, l = t & 63;
    const int jb = l * 6;                      // j base: 0..378
    float tdj[6], rdj[6];
    float dent[6] = {0.f, 0.f, 0.f, 0.f, 0.f, 0.f};
    float denh[6] = {0.f, 0.f, 0.f, 0.f, 0.f, 0.f};
#pragma unroll
    for (int jj = 0; jj < 6; ++jj) {
        float4 p = pks[jb + jj];
        tdj[jj] = p.x;
        rdj[jj] = p.y;
    }
    const int k0 = w * 48;
#pragma unroll 4
    for (int k = k0; k < k0 + 48; ++k) {
        float4 p = pks[k];  // wave-uniform -> broadcast, conflict-free
#pragma unroll
        for (int jj = 0; jj < 6; ++jj) {
            bool mt = p.x >= tdj[jj];
            bool mh = mt && (p.y >= rdj[jj]);
            dent[jj] += mt ? p.z : 0.f;
            denh[jj] += mh ? p.z : 0.f;
        }
    }
#pragma unroll
    for (int jj = 0; jj < 6; ++jj) {
        dpt[w][jb + jj] = dent[jj];
        dph[w][jb + jj] = denh[jj];
    }
    __syncthreads();

    float pos_h = 0.f, pos_t = 0.f;
    if (t < N && t != i) {
        float st_ = 0.f, sh_ = 0.f;
#pragma unroll
        for (int g = 0; g < 8; ++g) {
            st_ += dpt[g][t];   // consecutive t -> conflict-free
            sh_ += dph[g][t];
        }
        float lo = pks[t].w;
        pos_h = lo - logf(sh_ + EPS_LOG);
        pos_t = lo - logf(st_ + EPS_LOG);
    }
#pragma unroll
    for (int off = 32; off > 0; off >>= 1) {
        pos_h += __shfl_down(pos_h, off, 64);
        pos_t += __shfl_down(pos_t, off, 64);
    }
    if (l == 0) {
        red_h[w] = pos_h;
        red_t[w] = pos_t;
    }
    __syncthreads();
    if (t == 0) {
        float sh = 0.f, st = 0.f;
#pragma unroll
        for (int g = 0; g < 8; ++g) {
            sh += red_h[g];
            st += red_t[g];
        }
        const float scale = -1.0f / ((float)N * (float)(N - 1));
        atomicAdd(out, (sh + SOFT_LAMBDA * st) * scale);
    }
}

extern "C" void kernel_launch(void* const* d_in, const int* in_sizes, int n_in,
                              void* d_out, int out_size, void* d_ws, size_t ws_size,
                              hipStream_t stream) {
    const float* feat = (const float*)d_in[0];  // [384,128]
    const float* rg   = (const float*)d_in[1];  // [384,3]
    const float* rr   = (const float*)d_in[2];  // [384,3]
    const float* tr   = (const float*)d_in[3];  // [384,3]
    const int*   sym  = (const int*)d_in[4];    // [384,1]
    float* out = (float*)d_out;

    float4* pk = (float4*)d_ws;  // 384*384*16 B = 2.36 MB

    dim3 gridA(N / TK, N / TI);
    rnc_pairs<<<gridA, 256, 0, stream>>>(feat, rg, rr, tr, sym, pk, out);
    rnc_rank<<<N, 512, 0, stream>>>(pk, out);
}